// Round 1
// baseline (9.500 us; speedup 1.0000x reference)
//
#include <hip/hip_runtime.h>

// Problem constants (from the reference):
//   B=64, F=128, T=512, C=10, D=128
// Mathematical identity: softmax(attn, axis=-1).mean(axis=-1) == 1/T exactly,
// so the reference reduces to:
//   out[b,c,f] = (1 + sigma) * mean_t inputs[b,f,t]
// independent of c, the weights, and the labels.

#define CSA_B 64
#define CSA_F 128
#define CSA_T 512
#define CSA_C 10

__global__ __launch_bounds__(256) void csa_mean_kernel(
    const float* __restrict__ inputs,   // [B,F,T]
    const float* __restrict__ sigma,    // [1]
    float* __restrict__ out)            // [B,C,F]
{
    const int gwave = (int)((blockIdx.x * blockDim.x + threadIdx.x) >> 6); // one wave per (b,f) row
    const int lane  = (int)(threadIdx.x & 63);
    const int nrows = CSA_B * CSA_F;
    if (gwave >= nrows) return;

    const float* row = inputs + (size_t)gwave * CSA_T;

    // 512 floats per row; 64 lanes * float4 = 256 floats per load -> 2 loads.
    const float4 a = *reinterpret_cast<const float4*>(row + lane * 4);
    const float4 b = *reinterpret_cast<const float4*>(row + 256 + lane * 4);
    float s = (a.x + a.y) + (a.z + a.w) + (b.x + b.y) + (b.z + b.w);

    // Butterfly reduce across the 64-lane wave: every lane ends with the row sum.
#pragma unroll
    for (int off = 1; off < 64; off <<= 1)
        s += __shfl_xor(s, off, 64);

    const float scale = (1.0f + sigma[0]) / (float)CSA_T;
    const float v = s * scale;

    const int bb = gwave >> 7;          // gwave / F  (F = 128)
    const int f  = gwave & (CSA_F - 1); // gwave % F

    // Broadcast over the class axis: lanes 0..C-1 each write one class slot.
    if (lane < CSA_C) {
        out[((size_t)bb * CSA_C + lane) * CSA_F + f] = v;
    }
}

extern "C" void kernel_launch(void* const* d_in, const int* in_sizes, int n_in,
                              void* d_out, int out_size, void* d_ws, size_t ws_size,
                              hipStream_t stream) {
    const float* inputs = (const float*)d_in[0]; // [B,F,T]
    // d_in[1..4] = key_w, key_b, query_w, query_b  (algebraically cancel; unused)
    const float* sigma  = (const float*)d_in[5];  // [1]
    // d_in[6] = labels, d_in[7] = iter_epoch      (unused)
    float* out = (float*)d_out;                   // [B,C,F] f32

    const int nrows = CSA_B * CSA_F;              // 8192 rows, 1 wave each
    const int block = 256;                        // 4 waves / block
    const int grid  = (nrows * 64 + block - 1) / block; // 2048 blocks

    csa_mean_kernel<<<grid, block, 0, stream>>>(inputs, sigma, out);
}

// Round 2
// 9.388 us; speedup vs baseline: 1.0119x; 1.0119x over previous
//
#include <hip/hip_runtime.h>

// Problem constants: B=64, F=128, T=512, C=10, D=128.
// Identity: softmax(attn, -1).mean(-1) == 1/T exactly, so
//   out[b,c,f] = (1 + sigma) * mean_t inputs[b,f,t]
// independent of c, weights, and labels. Pure row-mean + broadcast.

#define CSA_B 64
#define CSA_F 128
#define CSA_T 512
#define CSA_C 10

__global__ __launch_bounds__(256) void csa_mean_kernel(
    const float* __restrict__ inputs,   // [B,F,T]
    const float* __restrict__ sigma,    // [1]
    float* __restrict__ out)            // [B,C,F]
{
    // 2 rows per wave: 32 lanes per row, 16 floats (4x float4) per lane.
    const int gtid = (int)(blockIdx.x * blockDim.x + threadIdx.x);
    const int wave = gtid >> 6;               // 4096 waves
    const int lane = (int)(threadIdx.x & 63);
    const int half = lane >> 5;               // which of the 2 rows
    const int j    = lane & 31;               // lane within row
    const int row  = wave * 2 + half;         // (b,f) row index, < 8192

    const float* rp = inputs + (size_t)row * CSA_T + j * 4;
    // 4 independent float4 loads (ILP); each instruction is 2x512B coalesced.
    const float4 v0 = *reinterpret_cast<const float4*>(rp);
    const float4 v1 = *reinterpret_cast<const float4*>(rp + 128);
    const float4 v2 = *reinterpret_cast<const float4*>(rp + 256);
    const float4 v3 = *reinterpret_cast<const float4*>(rp + 384);

    float s = ((v0.x + v0.y) + (v0.z + v0.w)) + ((v1.x + v1.y) + (v1.z + v1.w))
            + ((v2.x + v2.y) + (v2.z + v2.w)) + ((v3.x + v3.y) + (v3.z + v3.w));

    // Butterfly within each 32-lane half (offsets < 32 never cross halves).
#pragma unroll
    for (int off = 1; off < 32; off <<= 1)
        s += __shfl_xor(s, off, 64);

    const float scale = (1.0f + sigma[0]) / (float)CSA_T;
    const float v = s * scale;

    const int bb = row >> 7;            // row / F
    const int f  = row & (CSA_F - 1);   // row % F

    // Broadcast over classes: 10 of the 32 lanes in this half write one slot.
    if (j < CSA_C) {
        out[((size_t)bb * CSA_C + j) * CSA_F + f] = v;
    }
}

extern "C" void kernel_launch(void* const* d_in, const int* in_sizes, int n_in,
                              void* d_out, int out_size, void* d_ws, size_t ws_size,
                              hipStream_t stream) {
    const float* inputs = (const float*)d_in[0]; // [B,F,T] f32
    const float* sigma  = (const float*)d_in[5]; // [1]
    float* out = (float*)d_out;                  // [B,C,F] f32

    const int nrows = CSA_B * CSA_F;             // 8192 rows
    const int waves = nrows / 2;                 // 4096 waves, 2 rows each
    const int block = 256;                       // 4 waves/block
    const int grid  = (waves * 64) / block;      // 1024 blocks

    csa_mean_kernel<<<grid, block, 0, stream>>>(inputs, sigma, out);
}